// Round 2
// baseline (227.218 us; speedup 1.0000x reference)
//
#include <hip/hip_runtime.h>
#include <math.h>

#define NC   1000                 // NUM_CLASSES
#define NVEC 250                  // float4 chunks per row (1000/4)
#define WPB  4                    // waves (=rows) per block
#define L2E  1.4426950408889634f  // log2(e)

typedef float v4f __attribute__((ext_vector_type(4)));   // native vec for nontemporal store

#if __has_builtin(__builtin_amdgcn_exp2f)
#define FAST_EXP2(x) __builtin_amdgcn_exp2f(x)   // v_exp_f32
#else
#define FAST_EXP2(x) exp2f(x)
#endif

#if __has_builtin(__builtin_amdgcn_rcpf)
#define FAST_RCP(x) __builtin_amdgcn_rcpf(x)     // v_rcp_f32
#else
#define FAST_RCP(x) (1.0f / (x))
#endif

__global__ __launch_bounds__(256)
void smooth_filter_kernel(const float* __restrict__ in,
                          float* __restrict__ out,
                          int rows) {
    const int lane = threadIdx.x & 63;
    const int row  = blockIdx.x * WPB + (threadIdx.x >> 6);
    if (row >= rows) return;                      // wave-uniform guard

    const float4* __restrict__ rp = (const float4*)(in  + (size_t)row * NC);
    v4f*          __restrict__ op = (v4f*)         (out + (size_t)row * NC);

    // ---- whole row into registers: 4 coalesced float4 loads in flight ----
    float4 v[4];
    v[3] = make_float4(0.f, 0.f, 0.f, 0.f);
    v[0] = rp[lane];
    v[1] = rp[lane + 64];
    v[2] = rp[lane + 128];
    const bool tail = (lane < (NVEC - 192));      // lanes 0..57 own chunk 3
    if (tail) v[3] = rp[lane + 192];

    // ---- per-lane partial sums: sum(r), sum(|r|), sum(r^2) ----
    float s_r = 0.f, s_a = 0.f, s_a2 = 0.f;
    #pragma unroll
    for (int k = 0; k < 4; ++k) {
        const float a0 = fabsf(v[k].x), a1 = fabsf(v[k].y);
        const float a2 = fabsf(v[k].z), a3 = fabsf(v[k].w);
        s_r  += (v[k].x + v[k].y) + (v[k].z + v[k].w);
        s_a  += (a0 + a1) + (a2 + a3);
        s_a2 += (a0 * a0 + a1 * a1) + (a2 * a2 + a3 * a3);
    }

    // ---- wave-64 butterfly: every lane ends with the row totals ----
    #pragma unroll
    for (int off = 32; off > 0; off >>= 1) {
        s_r  += __shfl_xor(s_r,  off, 64);
        s_a  += __shfl_xor(s_a,  off, 64);
        s_a2 += __shfl_xor(s_a2, off, 64);
    }

    // ---- row statistics (uniform across the wave) ----
    const float mean    = s_a * (1.0f / NC);
    const float var     = (s_a2 - (float)NC * mean * mean) * (1.0f / (NC - 1));
    const float inv_std = rsqrtf(var);

    // sigmoid((a-mean)*inv_std) = rcp(1 + exp2(a*kx + bx))
    const float kx = -inv_std * L2E;              // per-element: 1 FMA
    const float bx =  mean * inv_std * L2E;
    const float c  = 1.0f / (NC - 1);
    const float cS = c * s_r;                     // c * sum(r)
    const float cn = c * (float)NC;               // c * n

    // ---- fused epilogue: out = r + w*(cS - cn*r), w = sigmoid(...) ----
    #pragma unroll
    for (int k = 0; k < 4; ++k) {
        if (k == 3 && !tail) break;
        v4f o;
        {
            const float e = FAST_EXP2(fmaf(fabsf(v[k].x), kx, bx));
            o.x = fmaf(FAST_RCP(1.0f + e), fmaf(-cn, v[k].x, cS), v[k].x);
        }
        {
            const float e = FAST_EXP2(fmaf(fabsf(v[k].y), kx, bx));
            o.y = fmaf(FAST_RCP(1.0f + e), fmaf(-cn, v[k].y, cS), v[k].y);
        }
        {
            const float e = FAST_EXP2(fmaf(fabsf(v[k].z), kx, bx));
            o.z = fmaf(FAST_RCP(1.0f + e), fmaf(-cn, v[k].z, cS), v[k].z);
        }
        {
            const float e = FAST_EXP2(fmaf(fabsf(v[k].w), kx, bx));
            o.w = fmaf(FAST_RCP(1.0f + e), fmaf(-cn, v[k].w, cS), v[k].w);
        }
        // output is write-once, never re-read in the timed loop:
        // nontemporal keeps the 131 MB input resident in L3 instead
        __builtin_nontemporal_store(o, &op[lane + 64 * k]);
    }
}

extern "C" void kernel_launch(void* const* d_in, const int* in_sizes, int n_in,
                              void* d_out, int out_size, void* d_ws, size_t ws_size,
                              hipStream_t stream) {
    const float* in  = (const float*)d_in[0];
    float*       out = (float*)d_out;
    const int rows   = in_sizes[0] / NC;          // 32768
    const int blocks = (rows + WPB - 1) / WPB;    // 8192
    smooth_filter_kernel<<<blocks, 256, 0, stream>>>(in, out, rows);
}